// Round 8
// baseline (95.713 us; speedup 1.0000x reference)
//
#include <hip/hip_runtime.h>

#define NG 256
#define NPG 64
#define DM 64
#define DFF 256
#define NL 2
#define DEG 8
#define NCLS 10
#define S68 68
#define S132 132

// LDS pool offsets (u32 words)
#define HB0 0              // [64][68] packed-split h
#define AB0 4352           // [64][68] scratch (fp32 or packed struct)
#define BB0 8704           // [64][68] scratch
#define QB0 13056          // [64][68] q (fp32) then attn-out (packed)
#define F10 17408          // [64][132] packed f1 half
#define POOLW 25856        // 103.4 KB

// prepped weight buffer (u32 packed-split words)
#define W64B 0             // 12 matrices x 4096 words, [m][c][k]
#define FF1B 49152         // 2 layers x 16384, [lay][c(256)][k(64)]
#define FF2B 81920         // 2 layers x 16384, [lay][c(64)][k(256)]
#define WTOT 114688        // 458 KB

__device__ __align__(16) unsigned int g_w[WTOT];   // fallback if d_ws too small

typedef __attribute__((ext_vector_type(4))) float f32x4;
typedef __attribute__((ext_vector_type(4))) unsigned int u32x4;
typedef __attribute__((ext_vector_type(8))) __bf16 bf16x8;

// ---- split-bf16 packing: u32 = (lo16 << 16) | hi16,  x ~= hi + lo ----
__device__ __forceinline__ unsigned int packsplit(float x) {
    union { float f; unsigned int u; } a; a.f = x;
    const unsigned int t = a.u;
    const unsigned int hi = (t + 0x7FFFu + ((t >> 16) & 1u)) >> 16;   // RNE bf16(x)
    union { unsigned int u; float f; } hf; hf.u = hi << 16;
    union { float f; unsigned int u; } b; b.f = x - hf.f;
    const unsigned int tl = b.u;
    const unsigned int lo = (tl + 0x7FFFu + ((tl >> 16) & 1u)) & 0xFFFF0000u;
    return hi | lo;
}
__device__ __forceinline__ float unpackf(unsigned int u) {
    union { unsigned int u; float f; } h, l;
    h.u = u << 16;            // hi bits (low half) -> fp32
    l.u = u & 0xFFFF0000u;    // lo bits (high half) -> fp32
    return h.f + l.f;
}

// extract hi-frag / lo-frag (bf16x8 as u32x4) from 8 packed words
__device__ __forceinline__ void extract(u32x4 p0, u32x4 p1, u32x4& hi, u32x4& lo) {
    hi[0] = (p0[0] & 0xFFFFu) | (p0[1] << 16);
    hi[1] = (p0[2] & 0xFFFFu) | (p0[3] << 16);
    hi[2] = (p1[0] & 0xFFFFu) | (p1[1] << 16);
    hi[3] = (p1[2] & 0xFFFFu) | (p1[3] << 16);
    lo[0] = (p0[0] >> 16) | (p0[1] & 0xFFFF0000u);
    lo[1] = (p0[2] >> 16) | (p0[3] & 0xFFFF0000u);
    lo[2] = (p1[0] >> 16) | (p1[1] & 0xFFFF0000u);
    lo[3] = (p1[2] >> 16) | (p1[3] & 0xFFFF0000u);
}

__device__ __forceinline__ f32x4 mfma16(u32x4 a, u32x4 b, f32x4 c) {
    return __builtin_amdgcn_mfma_f32_16x16x32_bf16(
        __builtin_bit_cast(bf16x8, a), __builtin_bit_cast(bf16x8, b), c, 0, 0, 0);
}

// one K=32 chunk: acc += A_chunk (LDS packed) * B_chunk (global packed), 3 MFMAs
__device__ __forceinline__ f32x4 mmchunk(const unsigned int* Ap, const unsigned int* Bp,
                                         f32x4 acc) {
    const u32x4 a0 = *(const u32x4*)Ap, a1 = *(const u32x4*)(Ap + 4);
    const u32x4 b0 = *(const u32x4*)Bp, b1 = *(const u32x4*)(Bp + 4);
    u32x4 ah, al, bh, bl;
    extract(a0, a1, ah, al);
    extract(b0, b1, bh, bl);
    acc = mfma16(ah, bh, acc);
    acc = mfma16(ah, bl, acc);
    acc = mfma16(al, bh, acc);
    return acc;
}

// D-tile [16x16] at (wr,wc) of C = A[64x64]*W[64x64]; A packed LDS, W packed global [c][k]
__device__ __forceinline__ f32x4 mm64g(const unsigned int* Apk, const unsigned int* Wg,
                                       int wr, int wc, int l) {
    const int arow = (wr << 4) + (l & 15);
    const int bcol = (wc << 4) + (l & 15);
    const int kg = (l >> 4) << 3;
    f32x4 acc = {0.f, 0.f, 0.f, 0.f};
    acc = mmchunk(Apk + arow * S68 + kg,      Wg + bcol * 64 + kg,      acc);
    acc = mmchunk(Apk + arow * S68 + kg + 32, Wg + bcol * 64 + kg + 32, acc);
    return acc;
}

__device__ __forceinline__ void dwrite_f32(float* dst, f32x4 acc, int wr, int wc, int l) {
    const int col = (wc << 4) + (l & 15);
    const int r0 = (wr << 4) + ((l >> 4) << 2);
#pragma unroll
    for (int r = 0; r < 4; ++r) dst[(r0 + r) * S68 + col] = acc[r];
}

__device__ __forceinline__ void layernorm(const float* src, unsigned int* dst,
                                          const float* gp, const float* bp, int n, int jg) {
    const f32x4 v = *(const f32x4*)(src + n * S68 + jg);
    float s1 = v[0] + v[1] + v[2] + v[3];
    float s2 = v[0]*v[0] + v[1]*v[1] + v[2]*v[2] + v[3]*v[3];
    s1 += __shfl_xor(s1, 1); s1 += __shfl_xor(s1, 2);
    s1 += __shfl_xor(s1, 4); s1 += __shfl_xor(s1, 8);
    s2 += __shfl_xor(s2, 1); s2 += __shfl_xor(s2, 2);
    s2 += __shfl_xor(s2, 4); s2 += __shfl_xor(s2, 8);
    const float mean = s1 * 0.015625f;
    const float var  = s2 * 0.015625f - mean * mean;
    const float rstd = rsqrtf(var + 1e-5f);
    const f32x4 gm = *(const f32x4*)(gp + jg);
    const f32x4 bt = *(const f32x4*)(bp + jg);
    u32x4 p;
#pragma unroll
    for (int j = 0; j < 4; ++j) p[j] = packsplit((v[j] - mean) * rstd * gm[j] + bt[j]);
    *(u32x4*)(dst + n * S68 + jg) = p;
}

// ---- weight prep: fp32 -> transposed packed split-bf16 words ----
extern "C" __global__ void gt_prep(const float* __restrict__ Wgn, const float* __restrict__ Wgs,
                                   const float* __restrict__ Wk, const float* __restrict__ Wq,
                                   const float* __restrict__ Wv, const float* __restrict__ Wo,
                                   const float* __restrict__ fW1, const float* __restrict__ fW2,
                                   unsigned int* wout)
{
    unsigned int* W = wout ? wout : g_w;
    const int t = blockIdx.x * 256 + threadIdx.x;   // 0..114687 == WTOT
    float v; int d;
    if (t < 49152) {
        const int m = t >> 12, r = t & 4095, k = r >> 6, c = r & 63;
        const int lay = m / 6, idx = m - lay * 6;
        const float* s;
        switch (idx) { case 0: s = Wgn; break; case 1: s = Wgs; break;
                       case 2: s = Wk;  break; case 3: s = Wq;  break;
                       case 4: s = Wv;  break; default: s = Wo; }
        v = s[lay * 4096 + k * 64 + c];
        d = (m << 12) + (c << 6) + k;                    // [m][c][k]
    } else if (t < 81920) {
        const int r = t - 49152, lay = r >> 14, q = r & 16383, k = q >> 8, c = q & 255;
        v = fW1[lay * 16384 + k * 256 + c];
        d = FF1B + lay * 16384 + (c << 6) + k;           // [lay][c][k]
    } else {
        const int r = t - 81920, lay = r >> 14, q = r & 16383, k = q >> 6, c = q & 63;
        v = fW2[lay * 16384 + k * 64 + c];
        d = FF2B + lay * 16384 + (c << 8) + k;           // [lay][c][k]
    }
    W[d] = packsplit(v);
}

extern "C" __global__ __launch_bounds__(1024)
void gt_main(const int* __restrict__ x, const int* __restrict__ e_src,
             const float* __restrict__ emb, const float* __restrict__ bo,
             const float* __restrict__ l1g, const float* __restrict__ l1b,
             const float* __restrict__ fb1, const float* __restrict__ fb2,
             const float* __restrict__ l2g, const float* __restrict__ l2b,
             const float* __restrict__ cW1, const float* __restrict__ cb1,
             const float* __restrict__ cW2, const float* __restrict__ cb2,
             const unsigned int* __restrict__ wext,
             float* __restrict__ out)
{
    const unsigned int* gw = wext ? wext : g_w;

    __shared__ __align__(16) unsigned int pool[POOLW];
    unsigned int* Hb  = pool + HB0;
    unsigned int* Abu = pool + AB0;  float* Abf = (float*)Abu;
    unsigned int* Bbu = pool + BB0;  float* Bbf = (float*)Bbu;
    unsigned int* Qbu = pool + QB0;  float* Qbf = (float*)Qbu;
    unsigned int* F1  = pool + F10;

    const int g = blockIdx.x, tid = threadIdx.x;
    const int w = tid >> 6, l = tid & 63;
    const int wr = w >> 2, wc = w & 3;
    const int n = tid >> 4, jg = (tid & 15) << 2;

    // ---- h = emb[x] (packed) ----
    {
        const int lbl = x[g * NPG + n];
        const f32x4 e = *(const f32x4*)(emb + lbl * DM + jg);
        u32x4 p;
#pragma unroll
        for (int j = 0; j < 4; ++j) p[j] = packsplit(e[j]);
        *(u32x4*)(Hb + n * S68 + jg) = p;
    }
    __syncthreads();

    for (int lay = 0; lay < NL; ++lay) {
        const int m0 = lay * 6;

        // p1: T = h @ Wg_nbr -> Abf
        { f32x4 acc = mm64g(Hb, gw + ((m0 + 0) << 12), wr, wc, l); dwrite_f32(Abf, acc, wr, wc, l); }
        __syncthreads();

        // p2: agg over 8 incoming edges -> Bbf
        {
            f32x4 s = {0.f, 0.f, 0.f, 0.f};
            const int* es = e_src + (g * NPG + n) * DEG;
#pragma unroll
            for (int k = 0; k < DEG; ++k) {
                const int sr = es[k] - g * NPG;
                const f32x4 v4 = *(const f32x4*)(Abf + sr * S68 + jg);
                s[0] += v4[0]; s[1] += v4[1]; s[2] += v4[2]; s[3] += v4[3];
            }
            *(f32x4*)(Bbf + n * S68 + jg) = s;
        }
        __syncthreads();

        // p3: struct = h + relu(h @ Wg_self + agg) -> Abu (packed)
        {
            f32x4 acc = mm64g(Hb, gw + ((m0 + 1) << 12), wr, wc, l);
            const int col = (wc << 4) + (l & 15), r0 = (wr << 4) + ((l >> 4) << 2);
#pragma unroll
            for (int r = 0; r < 4; ++r) {
                const int row = r0 + r;
                const float v = fmaxf(acc[r] + Bbf[row * S68 + col], 0.f)
                                + unpackf(Hb[row * S68 + col]);
                Abu[row * S68 + col] = packsplit(v);
            }
        }
        __syncthreads();

        // p4a: k = struct @ Wk -> Bbf ; q = struct @ Wq -> Qbf
        {
            f32x4 acc = mm64g(Abu, gw + ((m0 + 2) << 12), wr, wc, l);
            dwrite_f32(Bbf, acc, wr, wc, l);
            f32x4 acq = mm64g(Abu, gw + ((m0 + 3) << 12), wr, wc, l);
            dwrite_f32(Qbf, acq, wr, wc, l);
        }
        __syncthreads();
        // p4b: v = h @ Wv -> Abf (overwrites struct)
        { f32x4 acc = mm64g(Hb, gw + ((m0 + 4) << 12), wr, wc, l); dwrite_f32(Abf, acc, wr, wc, l); }
        __syncthreads();

        // p5: attention (online softmax, round-4 exact); dst=n, head=(tid&15)>>2
        {
            const f32x4 qr = *(const f32x4*)(Qbf + n * S68 + jg);
            const float q0 = qr[0] * 0.25f, q1 = qr[1] * 0.25f;
            const float q2 = qr[2] * 0.25f, q3 = qr[3] * 0.25f;
            float o0 = 0.f, o1 = 0.f, o2 = 0.f, o3 = 0.f, m = -1e30f, ls = 0.f;
#pragma unroll 4
            for (int sr = 0; sr < NPG; ++sr) {
                const f32x4 k4 = *(const f32x4*)(Bbf + sr * S68 + jg);
                float s = q0*k4[0] + q1*k4[1] + q2*k4[2] + q3*k4[3];
                s += __shfl_xor(s, 1);
                s += __shfl_xor(s, 2);        // full 16-dim head dot (4 lanes)
                const float mn  = fmaxf(m, s);
                const float fac = __expf(m - mn), wg = __expf(s - mn);
                ls = ls * fac + wg;
                const f32x4 v4 = *(const f32x4*)(Abf + sr * S68 + jg);
                o0 = o0 * fac + wg * v4[0]; o1 = o1 * fac + wg * v4[1];
                o2 = o2 * fac + wg * v4[2]; o3 = o3 * fac + wg * v4[3];
                m = mn;
            }
            const float il = 1.f / ls;
            u32x4 p;
            p[0] = packsplit(o0 * il); p[1] = packsplit(o1 * il);
            p[2] = packsplit(o2 * il); p[3] = packsplit(o3 * il);
            *(u32x4*)(Qbu + n * S68 + jg) = p;   // lane-local overwrite of q
        }
        __syncthreads();

        // p6: o = attn @ Wo + bo + h -> Abf (pre-LN1)
        {
            f32x4 acc = mm64g(Qbu, gw + ((m0 + 5) << 12), wr, wc, l);
            const int col = (wc << 4) + (l & 15), r0 = (wr << 4) + ((l >> 4) << 2);
            const float bb = bo[lay * DM + col];
#pragma unroll
            for (int r = 0; r < 4; ++r) {
                const int row = r0 + r;
                Abf[row * S68 + col] = acc[r] + bb + unpackf(Hb[row * S68 + col]);
            }
        }
        __syncthreads();

        layernorm(Abf, Hb, l1g + lay * DM, l1b + lay * DM, n, jg);
        __syncthreads();

        // ---- FF in 2 halves of 128 hidden ----
        f32x4 f2 = {0.f, 0.f, 0.f, 0.f};
        for (int hf = 0; hf < 2; ++hf) {
            // FF1: 2 col-tiles per wave; relu; -> F1 packed [64][132]
            {
                const int kg = (l >> 4) << 3, arow = (wr << 4) + (l & 15);
                const int r0 = (wr << 4) + ((l >> 4) << 2);
#pragma unroll
                for (int t = 0; t < 2; ++t) {
                    const int tc = ((wc + 4 * t) << 4) + (l & 15);  // col within half (0..127)
                    const unsigned int* Bp = gw + FF1B + lay * 16384 + ((hf * 128 + tc) << 6) + kg;
                    f32x4 acc = {0.f, 0.f, 0.f, 0.f};
                    acc = mmchunk(Hb + arow * S68 + kg,      Bp,      acc);
                    acc = mmchunk(Hb + arow * S68 + kg + 32, Bp + 32, acc);
                    const float b1 = fb1[lay * DFF + hf * 128 + tc];
#pragma unroll
                    for (int r = 0; r < 4; ++r)
                        F1[(r0 + r) * S132 + tc] = packsplit(fmaxf(acc[r] + b1, 0.f));
                }
            }
            __syncthreads();
            // FF2: K=128 of this half, accumulate into f2
            {
                const int kg = (l >> 4) << 3;
                const int arow = (wr << 4) + (l & 15), bcol = (wc << 4) + (l & 15);
                const unsigned int* Bp = gw + FF2B + lay * 16384 + (bcol << 8) + hf * 128 + kg;
#pragma unroll
                for (int ch = 0; ch < 4; ++ch)
                    f2 = mmchunk(F1 + arow * S132 + kg + 32 * ch, Bp + 32 * ch, f2);
            }
            __syncthreads();   // before next half overwrites F1
        }
        // FF2 epilogue: + b2 + h -> Abf (pre-LN2)
        {
            const int col = (wc << 4) + (l & 15), r0 = (wr << 4) + ((l >> 4) << 2);
            const float bb = fb2[lay * DM + col];
#pragma unroll
            for (int r = 0; r < 4; ++r) {
                const int row = r0 + r;
                Abf[row * S68 + col] = f2[r] + bb + unpackf(Hb[row * S68 + col]);
            }
        }
        __syncthreads();

        layernorm(Abf, Hb, l2g + lay * DM, l2b + lay * DM, n, jg);
        __syncthreads();
    }

    // ---- mean pool + classifier ----
    if (tid < DM) {
        float s = 0.f;
        for (int nn = 0; nn < NPG; ++nn) s += unpackf(Hb[nn * S68 + tid]);
        Abf[tid] = s * 0.015625f;
    }
    __syncthreads();
    if (tid < DM) {
        float acc = cb1[tid];
        for (int i = 0; i < DM; ++i) acc = fmaf(Abf[i], cW1[i * DM + tid], acc);
        Bbf[tid] = fmaxf(acc, 0.f);
    }
    __syncthreads();
    if (tid < NCLS) {
        float acc = cb2[tid];
        for (int i = 0; i < DM; ++i) acc = fmaf(Bbf[i], cW2[i * NCLS + tid], acc);
        out[g * NCLS + tid] = acc;
    }
}

extern "C" void kernel_launch(void* const* d_in, const int* in_sizes, int n_in,
                              void* d_out, int out_size, void* d_ws, size_t ws_size,
                              hipStream_t stream) {
    // dict order: x0 e1 c2 b3 emb4 Wgs5 Wgn6 Wq7 Wk8 Wv9 Wo10 bo11 l1g12 l1b13
    //             fW1_14 fb1_15 fW2_16 fb2_17 l2g18 l2b19 cW1_20 cb1_21 cW2_22 cb2_23
    unsigned int* wbuf =
        (d_ws != nullptr && ws_size >= (size_t)WTOT * 4) ? (unsigned int*)d_ws : nullptr;
    gt_prep<<<dim3(448), dim3(256), 0, stream>>>(
        (const float*)d_in[6], (const float*)d_in[5],   // Wgn, Wgs
        (const float*)d_in[8], (const float*)d_in[7],   // Wk, Wq
        (const float*)d_in[9], (const float*)d_in[10],  // Wv, Wo
        (const float*)d_in[14], (const float*)d_in[16],
        wbuf);
    gt_main<<<dim3(NG), dim3(1024), 0, stream>>>(
        (const int*)d_in[0], (const int*)d_in[1],
        (const float*)d_in[4], (const float*)d_in[11],
        (const float*)d_in[12], (const float*)d_in[13],
        (const float*)d_in[15], (const float*)d_in[17],
        (const float*)d_in[18], (const float*)d_in[19],
        (const float*)d_in[20], (const float*)d_in[21],
        (const float*)d_in[22], (const float*)d_in[23],
        wbuf,
        (float*)d_out);
}